// Round 1
// baseline (35432.516 us; speedup 1.0000x reference)
//
#include <hip/hip_runtime.h>
#include <stdint.h>

#define T_SEQ 1024
#define BATCH 32
#define HID   512
#define G_WG  64      // workgroups in recurrent kernels
#define S_H   8       // h-slice per WG (512/64)

typedef unsigned short u16;
typedef short bf16x8 __attribute__((ext_vector_type(8)));   // 8 bf16 in 4 VGPRs (guide §3)
typedef float f32x4  __attribute__((ext_vector_type(4)));

__device__ __forceinline__ float bf2f(u16 u) {
  union { unsigned u; float f; } v; v.u = ((unsigned)u) << 16; return v.f;
}
__device__ __forceinline__ u16 f2bf(float f) {
  union { float f; unsigned u; } v; v.f = f;
  unsigned r = v.u + 0x7fffu + ((v.u >> 16) & 1u);   // RNE
  return (u16)(r >> 16);
}
__device__ __forceinline__ float sigf(float x) { return 1.0f / (1.0f + __expf(-x)); }
__device__ __forceinline__ float tanh_fast(float x) { return 2.0f * sigf(2.0f * x) - 1.0f; }

// ---------------- cast fp32 -> bf16 (8 elems/thread) ----------------
__global__ __launch_bounds__(256) void cast_f32_bf16(const float* __restrict__ in,
                                                     u16* __restrict__ out, int n) {
  int i = (blockIdx.x * 256 + threadIdx.x) * 8;
  if (i + 7 < n) {
    float4 v0 = *reinterpret_cast<const float4*>(in + i);
    float4 v1 = *reinterpret_cast<const float4*>(in + i + 4);
    uint4 o;
    o.x = (unsigned)f2bf(v0.x) | ((unsigned)f2bf(v0.y) << 16);
    o.y = (unsigned)f2bf(v0.z) | ((unsigned)f2bf(v0.w) << 16);
    o.z = (unsigned)f2bf(v1.x) | ((unsigned)f2bf(v1.y) << 16);
    o.w = (unsigned)f2bf(v1.z) | ((unsigned)f2bf(v1.w) << 16);
    *reinterpret_cast<uint4*>(out + i) = o;
  } else {
    for (; i < n; ++i) out[i] = f2bf(in[i]);
  }
}

// ---------------- xg GEMM: out[t][n][b] = A[row(m)][k] @ W[n][k]^T + bias ----------------
// m = t*32 + b ; A row index = (m&31)*strideB + (m>>5)*strideT
__global__ __launch_bounds__(256) void gemm_xg(
    const u16* __restrict__ A, const u16* __restrict__ W,
    const float* __restrict__ bias1, const float* __restrict__ bias2,
    u16* __restrict__ out, int N, int K, int strideB, int strideT)
{
  __shared__ u16 As[64][72];
  __shared__ u16 Bs[64][72];
  int tid  = threadIdx.x;
  int lane = tid & 63;
  int wave = tid >> 6;
  int m0 = blockIdx.x * 64;
  int n0 = blockIdx.y * 64;

  f32x4 zero = {0.f, 0.f, 0.f, 0.f};
  f32x4 acc[4] = {zero, zero, zero, zero};

  int srow = tid >> 2;           // 0..63
  int scol = (tid & 3) * 16;     // 0,16,32,48

  int m_s = m0 + srow;
  long arow = (long)(m_s & (BATCH - 1)) * strideB + (long)(m_s >> 5) * strideT;
  const u16* aptr = A + arow * K + scol;
  const u16* wptr = W + (long)(n0 + srow) * K + scol;

  for (int kk = 0; kk < K; kk += 64) {
    __syncthreads();
    uint4 a0 = *reinterpret_cast<const uint4*>(aptr + kk);
    uint4 a1 = *reinterpret_cast<const uint4*>(aptr + kk + 8);
    uint4 b0 = *reinterpret_cast<const uint4*>(wptr + kk);
    uint4 b1 = *reinterpret_cast<const uint4*>(wptr + kk + 8);
    *reinterpret_cast<uint4*>(&As[srow][scol])     = a0;
    *reinterpret_cast<uint4*>(&As[srow][scol + 8]) = a1;
    *reinterpret_cast<uint4*>(&Bs[srow][scol])     = b0;
    *reinterpret_cast<uint4*>(&Bs[srow][scol + 8]) = b1;
    __syncthreads();
    int am = wave * 16 + (lane & 15);
    int kq = (lane >> 4) * 8;
#pragma unroll
    for (int ks = 0; ks < 2; ++ks) {
      bf16x8 af = *reinterpret_cast<const bf16x8*>(&As[am][kq + ks * 32]);
#pragma unroll
      for (int nb = 0; nb < 4; ++nb) {
        bf16x8 bf = *reinterpret_cast<const bf16x8*>(&Bs[nb * 16 + (lane & 15)][kq + ks * 32]);
        acc[nb] = __builtin_amdgcn_mfma_f32_16x16x32_bf16(af, bf, acc[nb], 0, 0, 0);
      }
    }
  }
  int quad = lane >> 4;
#pragma unroll
  for (int nb = 0; nb < 4; ++nb) {
    int n = n0 + nb * 16 + (lane & 15);
    float bv = bias1[n] + (bias2 ? bias2[n] : 0.0f);
#pragma unroll
    for (int r = 0; r < 4; ++r) {
      int m = m0 + wave * 16 + quad * 4 + r;
      int t = m >> 5, b = m & (BATCH - 1);
      out[((long)t * N + n) * BATCH + b] = f2bf(acc[nb][r] + bv);
    }
  }
}

// ---------------- persistent recurrent kernel ----------------
// NG = gates per hidden unit: 4=LSTM, 3=GRU, 1=RNN-tanh
template <int NG>
__global__ __launch_bounds__(256) void recur_kernel(
    const u16* __restrict__ xg,    // [T][NG*512][B] bf16
    const u16* __restrict__ whh,   // [NG*512][512] bf16
    const float* __restrict__ bhh, // GRU: b_hh (3*512), else nullptr
    u16* __restrict__ hist,        // [T*32][512] bf16
    u16* __restrict__ hbuf0, u16* __restrict__ hbuf1,
    int* flags, int flag_base)
{
  constexpr int NPAD = (NG == 1) ? 16 : 32;
  constexpr int NROW = NG * 512;
  __shared__ u16 w_lds[NPAD][520];             // +8 pad: 2-way bank alias only (free)
  __shared__ float gates_lds[32][NPAD + 1];

  int tid  = threadIdx.x;
  int lane = tid & 63;
  int wave = tid >> 6;
  int wg    = blockIdx.x;         // 0..63
  int hbase = wg * S_H;

  // stage owned W_hh rows into LDS (zero-pad rows beyond NG*8)
  for (int idx = tid; idx < NPAD * 64; idx += 256) {
    int row = idx >> 6, chunk = idx & 63;
    uint4 v = make_uint4(0, 0, 0, 0);
    if (row < NG * 8) {
      int g = row >> 3, d = row & 7;
      v = *reinterpret_cast<const uint4*>(whh + (long)(g * 512 + hbase + d) * 512 + chunk * 8);
    }
    *reinterpret_cast<uint4*>(&w_lds[row][chunk * 8]) = v;
  }
  __syncthreads();

  int b = tid & 31;       // cell-phase batch
  int d = tid >> 5;       // cell-phase h offset within slice (0..7)
  float c_st = 0.0f;      // LSTM cell state (per-thread, never leaves registers)
  float h_st = 0.0f;      // GRU previous h
  float bh[NG];
#pragma unroll
  for (int g = 0; g < NG; ++g) bh[g] = bhh ? bhh[g * 512 + hbase + d] : 0.0f;

  int mt = wave & 1;
  int nt = wave >> 1;
  bool mfma_active = (nt * 16) < NPAD;

  for (int t = 0; t < T_SEQ; ++t) {
    // prefetch xg for this step (independent of h -> overlaps the poll)
    u16 xr[NG];
#pragma unroll
    for (int g = 0; g < NG; ++g)
      xr[g] = xg[((long)t * NROW + g * 512 + hbase + d) * BATCH + b];

    if (t > 0) {
      int target = flag_base + t;
      while (true) {
        int f = __hip_atomic_load(&flags[lane], __ATOMIC_RELAXED, __HIP_MEMORY_SCOPE_AGENT);
        if (__all(f >= target)) break;
        __builtin_amdgcn_s_sleep(1);
      }
      __threadfence();   // acquire: invalidate so h loads see remote writes
      if (mfma_active) {
        const u16* hin = (t & 1) ? hbuf1 : hbuf0;
        int arow = mt * 16 + (lane & 15);
        int kq = (lane >> 4) * 8;
        const u16* ap = hin + arow * HID + kq;
        bf16x8 af[16];
#pragma unroll
        for (int ks = 0; ks < 16; ++ks)
          af[ks] = *reinterpret_cast<const bf16x8*>(ap + ks * 32);
        int brow = nt * 16 + (lane & 15);
        f32x4 acc = {0.f, 0.f, 0.f, 0.f};
#pragma unroll
        for (int ks = 0; ks < 16; ++ks) {
          bf16x8 bf = *reinterpret_cast<const bf16x8*>(&w_lds[brow][kq + ks * 32]);
          acc = __builtin_amdgcn_mfma_f32_16x16x32_bf16(af[ks], bf, acc, 0, 0, 0);
        }
        int quad = lane >> 4;
#pragma unroll
        for (int r = 0; r < 4; ++r)
          gates_lds[mt * 16 + quad * 4 + r][nt * 16 + (lane & 15)] = acc[r];
      }
    }
    __syncthreads();

    // cell phase: thread (b,d) owns h[b][hbase+d]
    float hg[NG];
#pragma unroll
    for (int g = 0; g < NG; ++g)
      hg[g] = (t > 0) ? gates_lds[b][g * 8 + d] : 0.0f;
    float xv[NG];
#pragma unroll
    for (int g = 0; g < NG; ++g) xv[g] = bf2f(xr[g]);

    float hnew;
    if (NG == 4) {
      float i  = sigf(xv[0] + hg[0]);
      float f  = sigf(xv[1] + hg[1]);
      float g_ = tanh_fast(xv[2] + hg[2]);
      float o  = sigf(xv[3] + hg[3]);
      c_st = f * c_st + i * g_;
      hnew = o * tanh_fast(c_st);
    } else if (NG == 3) {
      float r = sigf(xv[0] + hg[0] + bh[0]);
      float z = sigf(xv[1] + hg[1] + bh[1]);
      float n = tanh_fast(xv[2] + r * (hg[2] + bh[2]));
      hnew = (1.0f - z) * n + z * h_st;
      h_st = hnew;
    } else {
      hnew = tanh_fast(xv[0] + hg[0]);
    }
    u16 hb = f2bf(hnew);
    u16* hout = (t & 1) ? hbuf0 : hbuf1;
    hout[b * HID + hbase + d] = hb;
    hist[((long)t * BATCH + b) * HID + hbase + d] = hb;
    __syncthreads();   // all stores issued (vmcnt drained at barrier) before flag
    if (tid == 0) {
      __threadfence();  // release: write back L2 so slices are device-visible
      __hip_atomic_store(&flags[wg], flag_base + t + 1, __ATOMIC_RELEASE, __HIP_MEMORY_SCOPE_AGENT);
    }
  }
}

// ---------------- LayerNorm over last dim (512), one wave per row ----------------
__global__ __launch_bounds__(256) void ln_kernel(
    const u16* __restrict__ in, const float* __restrict__ g,
    const float* __restrict__ b, u16* __restrict__ out, int nrows)
{
  int row  = blockIdx.x * 4 + (threadIdx.x >> 6);
  int lane = threadIdx.x & 63;
  if (row >= nrows) return;
  uint4 u = *reinterpret_cast<const uint4*>(in + (long)row * HID + lane * 8);
  u16* us = reinterpret_cast<u16*>(&u);
  float x[8];
#pragma unroll
  for (int i = 0; i < 8; ++i) x[i] = bf2f(us[i]);
  float s = 0;
#pragma unroll
  for (int i = 0; i < 8; ++i) s += x[i];
#pragma unroll
  for (int off = 1; off < 64; off <<= 1) s += __shfl_xor(s, off);
  float mu = s * (1.0f / HID);
  float v = 0;
#pragma unroll
  for (int i = 0; i < 8; ++i) { float dd = x[i] - mu; v += dd * dd; }
#pragma unroll
  for (int off = 1; off < 64; off <<= 1) v += __shfl_xor(v, off);
  float rs = rsqrtf(v * (1.0f / HID) + 1e-5f);
  float4 g0 = *reinterpret_cast<const float4*>(g + lane * 8);
  float4 g1 = *reinterpret_cast<const float4*>(g + lane * 8 + 4);
  float4 b0 = *reinterpret_cast<const float4*>(b + lane * 8);
  float4 b1 = *reinterpret_cast<const float4*>(b + lane * 8 + 4);
  float gg[8] = {g0.x, g0.y, g0.z, g0.w, g1.x, g1.y, g1.z, g1.w};
  float bb[8] = {b0.x, b0.y, b0.z, b0.w, b1.x, b1.y, b1.z, b1.w};
  u16 o[8];
#pragma unroll
  for (int i = 0; i < 8; ++i) o[i] = f2bf((x[i] - mu) * rs * gg[i] + bb[i]);
  *reinterpret_cast<uint4*>(out + (long)row * HID + lane * 8) = *reinterpret_cast<uint4*>(o);
}

// ---------------- final FC: out[b][o] = h_last . fc_w[o] + fc_b[o] ----------------
__global__ __launch_bounds__(256) void fc_kernel(
    const u16* __restrict__ hist, const u16* __restrict__ w,
    const float* __restrict__ bias, float* __restrict__ out)
{
  int tg = blockIdx.x * 256 + threadIdx.x;
  if (tg >= BATCH * 1000) return;
  int b = tg / 1000, o = tg % 1000;
  const u16* hp = hist + ((long)(T_SEQ - 1) * BATCH + b) * HID;
  const u16* wp = w + (long)o * HID;
  float acc = 0.f;
  for (int k = 0; k < HID; k += 8) {
    uint4 hu = *reinterpret_cast<const uint4*>(hp + k);
    uint4 wu = *reinterpret_cast<const uint4*>(wp + k);
    u16* hs = reinterpret_cast<u16*>(&hu);
    u16* ws = reinterpret_cast<u16*>(&wu);
#pragma unroll
    for (int i = 0; i < 8; ++i) acc += bf2f(hs[i]) * bf2f(ws[i]);
  }
  out[tg] = acc + bias[o];
}

__global__ void sentinel_kernel(float* out) { out[0] = 12345.0f; }

// ---------------- launch ----------------
extern "C" void kernel_launch(void* const* d_in, const int* in_sizes, int n_in,
                              void* d_out, int out_size, void* d_ws, size_t ws_size,
                              hipStream_t stream)
{
  (void)in_sizes; (void)n_in; (void)out_size;
  const float* x        = (const float*)d_in[0];
  const float* lstm_wih = (const float*)d_in[1];
  const float* lstm_whh = (const float*)d_in[2];
  const float* lstm_bih = (const float*)d_in[3];
  const float* lstm_bhh = (const float*)d_in[4];
  const float* ln1_g    = (const float*)d_in[5];
  const float* ln1_b    = (const float*)d_in[6];
  const float* gru_wih  = (const float*)d_in[7];
  const float* gru_whh  = (const float*)d_in[8];
  const float* gru_bih  = (const float*)d_in[9];
  const float* gru_bhh  = (const float*)d_in[10];
  const float* ln2_g    = (const float*)d_in[11];
  const float* ln2_b    = (const float*)d_in[12];
  const float* rnn_wih  = (const float*)d_in[13];
  const float* rnn_whh  = (const float*)d_in[14];
  const float* rnn_bih  = (const float*)d_in[15];
  const float* rnn_bhh  = (const float*)d_in[16];
  const float* fc_w     = (const float*)d_in[17];
  const float* fc_b     = (const float*)d_in[18];
  float* out = (float*)d_out;

  char* ws = (char*)d_ws;
  size_t off = 0;
  auto alloc = [&](size_t bytes) -> void* {
    void* p = ws + off; off += (bytes + 255) & ~(size_t)255; return p;
  };
  int* flags     = (int*)alloc(G_WG * sizeof(int));
  u16* hbuf0     = (u16*)alloc((size_t)BATCH * HID * 2);
  u16* hbuf1     = (u16*)alloc((size_t)BATCH * HID * 2);
  u16* xbf       = (u16*)alloc((size_t)BATCH * T_SEQ * 256 * 2);
  u16* lstm_wih_b= (u16*)alloc((size_t)2048 * 256 * 2);
  u16* lstm_whh_b= (u16*)alloc((size_t)2048 * 512 * 2);
  u16* gru_wih_b = (u16*)alloc((size_t)1536 * 512 * 2);
  u16* gru_whh_b = (u16*)alloc((size_t)1536 * 512 * 2);
  u16* rnn_wih_b = (u16*)alloc((size_t)512 * 512 * 2);
  u16* rnn_whh_b = (u16*)alloc((size_t)512 * 512 * 2);
  u16* fc_w_b    = (u16*)alloc((size_t)1000 * 512 * 2);
  u16* bufA      = (u16*)alloc((size_t)T_SEQ * BATCH * HID * 2);
  u16* bufB      = (u16*)alloc((size_t)T_SEQ * BATCH * HID * 2);
  u16* xg        = (u16*)alloc((size_t)T_SEQ * 2048 * BATCH * 2);

  if (off > ws_size) {  // ws too small: emit distinctive sentinel instead of corrupting
    sentinel_kernel<<<1, 1, 0, stream>>>(out);
    return;
  }

  hipMemsetAsync(flags, 0, G_WG * sizeof(int), stream);

  auto cast = [&](const float* src, u16* dst, int n) {
    cast_f32_bf16<<<(n + 2047) / 2048, 256, 0, stream>>>(src, dst, n);
  };
  cast(x,        xbf,        BATCH * T_SEQ * 256);
  cast(lstm_wih, lstm_wih_b, 2048 * 256);
  cast(lstm_whh, lstm_whh_b, 2048 * 512);
  cast(gru_wih,  gru_wih_b,  1536 * 512);
  cast(gru_whh,  gru_whh_b,  1536 * 512);
  cast(rnn_wih,  rnn_wih_b,  512 * 512);
  cast(rnn_whh,  rnn_whh_b,  512 * 512);
  cast(fc_w,     fc_w_b,     1000 * 512);

  const int M64 = (BATCH * T_SEQ) / 64;  // 512

  // ---- LSTM ----
  gemm_xg<<<dim3(M64, 2048 / 64), 256, 0, stream>>>(
      xbf, lstm_wih_b, lstm_bih, lstm_bhh, xg, 2048, 256, 1024, 1);
  recur_kernel<4><<<G_WG, 256, 0, stream>>>(
      xg, lstm_whh_b, nullptr, bufA, hbuf0, hbuf1, flags, 0);
  ln_kernel<<<(T_SEQ * BATCH) / 4, 256, 0, stream>>>(bufA, ln1_g, ln1_b, bufB, T_SEQ * BATCH);

  // ---- GRU ----
  gemm_xg<<<dim3(M64, 1536 / 64), 256, 0, stream>>>(
      bufB, gru_wih_b, gru_bih, nullptr, xg, 1536, 512, 1, 32);
  recur_kernel<3><<<G_WG, 256, 0, stream>>>(
      xg, gru_whh_b, gru_bhh, bufA, hbuf0, hbuf1, flags, 1024);
  ln_kernel<<<(T_SEQ * BATCH) / 4, 256, 0, stream>>>(bufA, ln2_g, ln2_b, bufB, T_SEQ * BATCH);

  // ---- RNN tanh ----
  gemm_xg<<<dim3(M64, 512 / 64), 256, 0, stream>>>(
      bufB, rnn_wih_b, rnn_bih, rnn_bhh, xg, 512, 512, 1, 32);
  recur_kernel<1><<<G_WG, 256, 0, stream>>>(
      xg, rnn_whh_b, nullptr, bufA, hbuf0, hbuf1, flags, 2048);

  // ---- FC ----
  fc_kernel<<<(BATCH * 1000 + 255) / 256, 256, 0, stream>>>(bufA, fc_w_b, fc_b, out);
}

// Round 2
// 18249.739 us; speedup vs baseline: 1.9415x; 1.9415x over previous
//
#include <hip/hip_runtime.h>
#include <stdint.h>

#define T_SEQ 1024
#define BATCH 32
#define HID   512
#define G_WG  64      // workgroups in recurrent kernels
#define S_H   8       // h-slice per WG (512/64)

typedef unsigned short u16;
typedef unsigned long long u64;
typedef short bf16x8 __attribute__((ext_vector_type(8)));   // 8 bf16 in 4 VGPRs
typedef float f32x4  __attribute__((ext_vector_type(4)));

__device__ __forceinline__ float bf2f(u16 u) {
  union { unsigned u; float f; } v; v.u = ((unsigned)u) << 16; return v.f;
}
__device__ __forceinline__ u16 f2bf(float f) {
  union { float f; unsigned u; } v; v.f = f;
  unsigned r = v.u + 0x7fffu + ((v.u >> 16) & 1u);   // RNE
  return (u16)(r >> 16);
}
__device__ __forceinline__ float sigf(float x) { return 1.0f / (1.0f + __expf(-x)); }
__device__ __forceinline__ float tanh_fast(float x) { return 2.0f * sigf(2.0f * x) - 1.0f; }

// Device-scope coherent 8B load/store: compile to global_load/store_dwordx2 sc1
// (write-through to / read from the device coherence point; bypass stale per-XCD L2).
// No buffer_wbl2 / buffer_inv is ever emitted for relaxed atomics.
__device__ __forceinline__ u64 ld_dev(const u64* p) {
  return __hip_atomic_load(p, __ATOMIC_RELAXED, __HIP_MEMORY_SCOPE_AGENT);
}
__device__ __forceinline__ void st_dev(u64* p, u64 v) {
  __hip_atomic_store(p, v, __ATOMIC_RELAXED, __HIP_MEMORY_SCOPE_AGENT);
}

// ---------------- cast fp32 -> bf16 (8 elems/thread) ----------------
__global__ __launch_bounds__(256) void cast_f32_bf16(const float* __restrict__ in,
                                                     u16* __restrict__ out, int n) {
  int i = (blockIdx.x * 256 + threadIdx.x) * 8;
  if (i + 7 < n) {
    float4 v0 = *reinterpret_cast<const float4*>(in + i);
    float4 v1 = *reinterpret_cast<const float4*>(in + i + 4);
    uint4 o;
    o.x = (unsigned)f2bf(v0.x) | ((unsigned)f2bf(v0.y) << 16);
    o.y = (unsigned)f2bf(v0.z) | ((unsigned)f2bf(v0.w) << 16);
    o.z = (unsigned)f2bf(v1.x) | ((unsigned)f2bf(v1.y) << 16);
    o.w = (unsigned)f2bf(v1.z) | ((unsigned)f2bf(v1.w) << 16);
    *reinterpret_cast<uint4*>(out + i) = o;
  } else {
    for (; i < n; ++i) out[i] = f2bf(in[i]);
  }
}

// ---------------- xg GEMM: out[t][n][b] = A[row(m)][k] @ W[n][k]^T + bias ----------------
// m = t*32 + b ; A row index = (m&31)*strideB + (m>>5)*strideT
__global__ __launch_bounds__(256) void gemm_xg(
    const u16* __restrict__ A, const u16* __restrict__ W,
    const float* __restrict__ bias1, const float* __restrict__ bias2,
    u16* __restrict__ out, int N, int K, int strideB, int strideT)
{
  __shared__ u16 As[64][72];
  __shared__ u16 Bs[64][72];
  int tid  = threadIdx.x;
  int lane = tid & 63;
  int wave = tid >> 6;
  int m0 = blockIdx.x * 64;
  int n0 = blockIdx.y * 64;

  f32x4 zero = {0.f, 0.f, 0.f, 0.f};
  f32x4 acc[4] = {zero, zero, zero, zero};

  int srow = tid >> 2;           // 0..63
  int scol = (tid & 3) * 16;     // 0,16,32,48

  int m_s = m0 + srow;
  long arow = (long)(m_s & (BATCH - 1)) * strideB + (long)(m_s >> 5) * strideT;
  const u16* aptr = A + arow * K + scol;
  const u16* wptr = W + (long)(n0 + srow) * K + scol;

  for (int kk = 0; kk < K; kk += 64) {
    __syncthreads();
    uint4 a0 = *reinterpret_cast<const uint4*>(aptr + kk);
    uint4 a1 = *reinterpret_cast<const uint4*>(aptr + kk + 8);
    uint4 b0 = *reinterpret_cast<const uint4*>(wptr + kk);
    uint4 b1 = *reinterpret_cast<const uint4*>(wptr + kk + 8);
    *reinterpret_cast<uint4*>(&As[srow][scol])     = a0;
    *reinterpret_cast<uint4*>(&As[srow][scol + 8]) = a1;
    *reinterpret_cast<uint4*>(&Bs[srow][scol])     = b0;
    *reinterpret_cast<uint4*>(&Bs[srow][scol + 8]) = b1;
    __syncthreads();
    int am = wave * 16 + (lane & 15);
    int kq = (lane >> 4) * 8;
#pragma unroll
    for (int ks = 0; ks < 2; ++ks) {
      bf16x8 af = *reinterpret_cast<const bf16x8*>(&As[am][kq + ks * 32]);
#pragma unroll
      for (int nb = 0; nb < 4; ++nb) {
        bf16x8 bf = *reinterpret_cast<const bf16x8*>(&Bs[nb * 16 + (lane & 15)][kq + ks * 32]);
        acc[nb] = __builtin_amdgcn_mfma_f32_16x16x32_bf16(af, bf, acc[nb], 0, 0, 0);
      }
    }
  }
  int quad = lane >> 4;
#pragma unroll
  for (int nb = 0; nb < 4; ++nb) {
    int n = n0 + nb * 16 + (lane & 15);
    float bv = bias1[n] + (bias2 ? bias2[n] : 0.0f);
#pragma unroll
    for (int r = 0; r < 4; ++r) {
      int m = m0 + wave * 16 + quad * 4 + r;
      int t = m >> 5, b = m & (BATCH - 1);
      out[((long)t * N + n) * BATCH + b] = f2bf(acc[nb][r] + bv);
    }
  }
}

// ---------------- persistent recurrent kernel ----------------
// NG = gates per hidden unit: 4=LSTM, 3=GRU, 1=RNN-tanh
// h history lives ONLY in hist[t][b][hid]; exchanged via device-scope atomics
// (no __threadfence -> no buffer_wbl2/buffer_inv L2 maintenance per step).
template <int NG>
__global__ __launch_bounds__(256) void recur_kernel(
    const u16* __restrict__ xg,    // [T][NG*512][B] bf16
    const u16* __restrict__ whh,   // [NG*512][512] bf16
    const float* __restrict__ bhh, // GRU: b_hh (3*512), else nullptr
    u16* __restrict__ hist,        // [T][32][512] bf16 (also the layer output)
    int* flags, int flag_base)
{
  constexpr int NPAD = (NG == 1) ? 16 : 32;
  constexpr int NROW = NG * 512;
  __shared__ u16 w_lds[NPAD][520];             // +8 pad: 2-way bank alias only (free)
  __shared__ float gates_lds[32][NPAD + 1];
  __shared__ u16 hs_lds[32][8];                // this WG's h slice for the step

  int tid  = threadIdx.x;
  int lane = tid & 63;
  int wave = tid >> 6;
  int wg    = blockIdx.x;         // 0..63
  int hbase = wg * S_H;

  // stage owned W_hh rows into LDS (zero-pad rows beyond NG*8)
  for (int idx = tid; idx < NPAD * 64; idx += 256) {
    int row = idx >> 6, chunk = idx & 63;
    uint4 v = make_uint4(0, 0, 0, 0);
    if (row < NG * 8) {
      int g = row >> 3, d = row & 7;
      v = *reinterpret_cast<const uint4*>(whh + (long)(g * 512 + hbase + d) * 512 + chunk * 8);
    }
    *reinterpret_cast<uint4*>(&w_lds[row][chunk * 8]) = v;
  }
  __syncthreads();

  int b = tid & 31;       // cell-phase batch
  int d = tid >> 5;       // cell-phase h offset within slice (0..7)
  float c_st = 0.0f;      // LSTM cell state (registers only)
  float h_st = 0.0f;      // GRU previous h
  float bh[NG];
#pragma unroll
  for (int g = 0; g < NG; ++g) bh[g] = bhh ? bhh[g * 512 + hbase + d] : 0.0f;

  int mt = wave & 1;
  int nt = wave >> 1;
  bool mfma_active = (nt * 16) < NPAD;

  for (int t = 0; t < T_SEQ; ++t) {
    // prefetch xg for this step (independent of h -> overlaps the poll)
    u16 xr[NG];
#pragma unroll
    for (int g = 0; g < NG; ++g)
      xr[g] = xg[((long)t * NROW + g * 512 + hbase + d) * BATCH + b];

    if (t > 0) {
      if (mfma_active) {
        int target = flag_base + t;
        while (true) {
          int f = __hip_atomic_load(&flags[lane], __ATOMIC_RELAXED, __HIP_MEMORY_SCOPE_AGENT);
          if (__all(f >= target)) break;
          __builtin_amdgcn_s_sleep(1);
        }
        __asm__ volatile("" ::: "memory");   // keep data loads after the poll
        // load A fragments (h_{t-1}) coherently: 32 x 8B device-scope loads
        const u64* hin = reinterpret_cast<const u64*>(hist + (long)(t - 1) * BATCH * HID);
        int arow = mt * 16 + (lane & 15);
        int kq = (lane >> 4) * 8;
        const u64* ap = hin + (arow * HID + kq) / 4;
        u64 araw[32];
#pragma unroll
        for (int ks = 0; ks < 16; ++ks) {
          araw[2 * ks]     = ld_dev(ap + ks * 8);
          araw[2 * ks + 1] = ld_dev(ap + ks * 8 + 1);
        }
        int brow = nt * 16 + (lane & 15);
        f32x4 acc = {0.f, 0.f, 0.f, 0.f};
#pragma unroll
        for (int ks = 0; ks < 16; ++ks) {
          union { u64 q[2]; bf16x8 v; } cvt;
          cvt.q[0] = araw[2 * ks]; cvt.q[1] = araw[2 * ks + 1];
          bf16x8 bf = *reinterpret_cast<const bf16x8*>(&w_lds[brow][kq + ks * 32]);
          acc = __builtin_amdgcn_mfma_f32_16x16x32_bf16(cvt.v, bf, acc, 0, 0, 0);
        }
        int quad = lane >> 4;
#pragma unroll
        for (int r = 0; r < 4; ++r)
          gates_lds[mt * 16 + quad * 4 + r][nt * 16 + (lane & 15)] = acc[r];
      }
    }
    __syncthreads();

    // cell phase: thread (b,d) owns h[b][hbase+d]
    float hg[NG];
#pragma unroll
    for (int g = 0; g < NG; ++g)
      hg[g] = (t > 0) ? gates_lds[b][g * 8 + d] : 0.0f;
    float xv[NG];
#pragma unroll
    for (int g = 0; g < NG; ++g) xv[g] = bf2f(xr[g]);

    float hnew;
    if (NG == 4) {
      float i  = sigf(xv[0] + hg[0]);
      float f  = sigf(xv[1] + hg[1]);
      float g_ = tanh_fast(xv[2] + hg[2]);
      float o  = sigf(xv[3] + hg[3]);
      c_st = f * c_st + i * g_;
      hnew = o * tanh_fast(c_st);
    } else if (NG == 3) {
      float r = sigf(xv[0] + hg[0] + bh[0]);
      float z = sigf(xv[1] + hg[1] + bh[1]);
      float n = tanh_fast(xv[2] + r * (hg[2] + bh[2]));
      hnew = (1.0f - z) * n + z * h_st;
      h_st = hnew;
    } else {
      hnew = tanh_fast(xv[0] + hg[0]);
    }
    hs_lds[b][d] = f2bf(hnew);
    __syncthreads();   // slice ready in LDS; gates_lds consumed

    // wave 0 publishes the slice: 64 lanes x 8B device-scope stores, then flag.
    if (wave == 0) {
      int pb = lane >> 1, half = lane & 1;
      u64 val = *reinterpret_cast<const u64*>(&hs_lds[pb][half * 4]);
      u64* hp = reinterpret_cast<u64*>(hist + ((long)t * BATCH + pb) * HID + hbase + half * 4);
      st_dev(hp, val);
      __asm__ volatile("s_waitcnt vmcnt(0)" ::: "memory");  // wave-0 stores visible
      if (tid == 0)
        __hip_atomic_store(&flags[wg], flag_base + t + 1,
                           __ATOMIC_RELAXED, __HIP_MEMORY_SCOPE_AGENT);
    }
  }
}

// ---------------- LayerNorm over last dim (512), one wave per row ----------------
__global__ __launch_bounds__(256) void ln_kernel(
    const u16* __restrict__ in, const float* __restrict__ g,
    const float* __restrict__ b, u16* __restrict__ out, int nrows)
{
  int row  = blockIdx.x * 4 + (threadIdx.x >> 6);
  int lane = threadIdx.x & 63;
  if (row >= nrows) return;
  uint4 u = *reinterpret_cast<const uint4*>(in + (long)row * HID + lane * 8);
  u16* us = reinterpret_cast<u16*>(&u);
  float x[8];
#pragma unroll
  for (int i = 0; i < 8; ++i) x[i] = bf2f(us[i]);
  float s = 0;
#pragma unroll
  for (int i = 0; i < 8; ++i) s += x[i];
#pragma unroll
  for (int off = 1; off < 64; off <<= 1) s += __shfl_xor(s, off);
  float mu = s * (1.0f / HID);
  float v = 0;
#pragma unroll
  for (int i = 0; i < 8; ++i) { float dd = x[i] - mu; v += dd * dd; }
#pragma unroll
  for (int off = 1; off < 64; off <<= 1) v += __shfl_xor(v, off);
  float rs = rsqrtf(v * (1.0f / HID) + 1e-5f);
  float4 g0 = *reinterpret_cast<const float4*>(g + lane * 8);
  float4 g1 = *reinterpret_cast<const float4*>(g + lane * 8 + 4);
  float4 b0 = *reinterpret_cast<const float4*>(b + lane * 8);
  float4 b1 = *reinterpret_cast<const float4*>(b + lane * 8 + 4);
  float gg[8] = {g0.x, g0.y, g0.z, g0.w, g1.x, g1.y, g1.z, g1.w};
  float bb[8] = {b0.x, b0.y, b0.z, b0.w, b1.x, b1.y, b1.z, b1.w};
  u16 o[8];
#pragma unroll
  for (int i = 0; i < 8; ++i) o[i] = f2bf((x[i] - mu) * rs * gg[i] + bb[i]);
  *reinterpret_cast<uint4*>(out + (long)row * HID + lane * 8) = *reinterpret_cast<uint4*>(o);
}

// ---------------- final FC: out[b][o] = h_last . fc_w[o] + fc_b[o] ----------------
__global__ __launch_bounds__(256) void fc_kernel(
    const u16* __restrict__ hist, const u16* __restrict__ w,
    const float* __restrict__ bias, float* __restrict__ out)
{
  int tg = blockIdx.x * 256 + threadIdx.x;
  if (tg >= BATCH * 1000) return;
  int b = tg / 1000, o = tg % 1000;
  const u16* hp = hist + ((long)(T_SEQ - 1) * BATCH + b) * HID;
  const u16* wp = w + (long)o * HID;
  float acc = 0.f;
  for (int k = 0; k < HID; k += 8) {
    uint4 hu = *reinterpret_cast<const uint4*>(hp + k);
    uint4 wu = *reinterpret_cast<const uint4*>(wp + k);
    u16* hs = reinterpret_cast<u16*>(&hu);
    u16* ws = reinterpret_cast<u16*>(&wu);
#pragma unroll
    for (int i = 0; i < 8; ++i) acc += bf2f(hs[i]) * bf2f(ws[i]);
  }
  out[tg] = acc + bias[o];
}

__global__ void sentinel_kernel(float* out) { out[0] = 12345.0f; }

// ---------------- launch ----------------
extern "C" void kernel_launch(void* const* d_in, const int* in_sizes, int n_in,
                              void* d_out, int out_size, void* d_ws, size_t ws_size,
                              hipStream_t stream)
{
  (void)in_sizes; (void)n_in; (void)out_size;
  const float* x        = (const float*)d_in[0];
  const float* lstm_wih = (const float*)d_in[1];
  const float* lstm_whh = (const float*)d_in[2];
  const float* lstm_bih = (const float*)d_in[3];
  const float* lstm_bhh = (const float*)d_in[4];
  const float* ln1_g    = (const float*)d_in[5];
  const float* ln1_b    = (const float*)d_in[6];
  const float* gru_wih  = (const float*)d_in[7];
  const float* gru_whh  = (const float*)d_in[8];
  const float* gru_bih  = (const float*)d_in[9];
  const float* gru_bhh  = (const float*)d_in[10];
  const float* ln2_g    = (const float*)d_in[11];
  const float* ln2_b    = (const float*)d_in[12];
  const float* rnn_wih  = (const float*)d_in[13];
  const float* rnn_whh  = (const float*)d_in[14];
  const float* rnn_bih  = (const float*)d_in[15];
  const float* rnn_bhh  = (const float*)d_in[16];
  const float* fc_w     = (const float*)d_in[17];
  const float* fc_b     = (const float*)d_in[18];
  float* out = (float*)d_out;

  char* ws = (char*)d_ws;
  size_t off = 0;
  auto alloc = [&](size_t bytes) -> void* {
    void* p = ws + off; off += (bytes + 255) & ~(size_t)255; return p;
  };
  int* flags     = (int*)alloc(G_WG * sizeof(int));
  u16* xbf       = (u16*)alloc((size_t)BATCH * T_SEQ * 256 * 2);
  u16* lstm_wih_b= (u16*)alloc((size_t)2048 * 256 * 2);
  u16* lstm_whh_b= (u16*)alloc((size_t)2048 * 512 * 2);
  u16* gru_wih_b = (u16*)alloc((size_t)1536 * 512 * 2);
  u16* gru_whh_b = (u16*)alloc((size_t)1536 * 512 * 2);
  u16* rnn_wih_b = (u16*)alloc((size_t)512 * 512 * 2);
  u16* rnn_whh_b = (u16*)alloc((size_t)512 * 512 * 2);
  u16* fc_w_b    = (u16*)alloc((size_t)1000 * 512 * 2);
  u16* bufA      = (u16*)alloc((size_t)T_SEQ * BATCH * HID * 2);
  u16* bufB      = (u16*)alloc((size_t)T_SEQ * BATCH * HID * 2);
  u16* xg        = (u16*)alloc((size_t)T_SEQ * 2048 * BATCH * 2);

  if (off > ws_size) {  // ws too small: emit distinctive sentinel instead of corrupting
    sentinel_kernel<<<1, 1, 0, stream>>>(out);
    return;
  }

  hipMemsetAsync(flags, 0, G_WG * sizeof(int), stream);

  auto cast = [&](const float* src, u16* dst, int n) {
    cast_f32_bf16<<<(n + 2047) / 2048, 256, 0, stream>>>(src, dst, n);
  };
  cast(x,        xbf,        BATCH * T_SEQ * 256);
  cast(lstm_wih, lstm_wih_b, 2048 * 256);
  cast(lstm_whh, lstm_whh_b, 2048 * 512);
  cast(gru_wih,  gru_wih_b,  1536 * 512);
  cast(gru_whh,  gru_whh_b,  1536 * 512);
  cast(rnn_wih,  rnn_wih_b,  512 * 512);
  cast(rnn_whh,  rnn_whh_b,  512 * 512);
  cast(fc_w,     fc_w_b,     1000 * 512);

  const int M64 = (BATCH * T_SEQ) / 64;  // 512

  // ---- LSTM ----
  gemm_xg<<<dim3(M64, 2048 / 64), 256, 0, stream>>>(
      xbf, lstm_wih_b, lstm_bih, lstm_bhh, xg, 2048, 256, 1024, 1);
  recur_kernel<4><<<G_WG, 256, 0, stream>>>(
      xg, lstm_whh_b, nullptr, bufA, flags, 0);
  ln_kernel<<<(T_SEQ * BATCH) / 4, 256, 0, stream>>>(bufA, ln1_g, ln1_b, bufB, T_SEQ * BATCH);

  // ---- GRU ----
  gemm_xg<<<dim3(M64, 1536 / 64), 256, 0, stream>>>(
      bufB, gru_wih_b, gru_bih, nullptr, xg, 1536, 512, 1, 32);
  recur_kernel<3><<<G_WG, 256, 0, stream>>>(
      xg, gru_whh_b, gru_bhh, bufA, flags, 1024);
  ln_kernel<<<(T_SEQ * BATCH) / 4, 256, 0, stream>>>(bufA, ln2_g, ln2_b, bufB, T_SEQ * BATCH);

  // ---- RNN tanh ----
  gemm_xg<<<dim3(M64, 512 / 64), 256, 0, stream>>>(
      bufB, rnn_wih_b, rnn_bih, rnn_bhh, xg, 512, 512, 1, 32);
  recur_kernel<1><<<G_WG, 256, 0, stream>>>(
      xg, rnn_whh_b, nullptr, bufA, flags, 2048);

  // ---- FC ----
  fc_kernel<<<(BATCH * 1000 + 255) / 256, 256, 0, stream>>>(bufA, fc_w_b, fc_b, out);
}

// Round 4
// 9962.167 us; speedup vs baseline: 3.5567x; 1.8319x over previous
//
#include <hip/hip_runtime.h>
#include <stdint.h>

#define T_SEQ 1024
#define BATCH 32
#define HID   512
#define RING  32     // inter-stage ring depth (power of 2)

typedef unsigned short u16;
typedef unsigned long long u64;
typedef short bf16x8 __attribute__((ext_vector_type(8)));
typedef float f32x4  __attribute__((ext_vector_type(4)));

__device__ __forceinline__ float bf2f(u16 u) {
  union { unsigned u; float f; } v; v.u = ((unsigned)u) << 16; return v.f;
}
__device__ __forceinline__ u16 f2bf(float f) {
  union { float f; unsigned u; } v; v.f = f;
  unsigned r = v.u + 0x7fffu + ((v.u >> 16) & 1u);   // RNE
  return (u16)(r >> 16);
}
__device__ __forceinline__ float sigf(float x) { return 1.0f / (1.0f + __expf(-x)); }
__device__ __forceinline__ float tanh_fast(float x) { return 2.0f * sigf(2.0f * x) - 1.0f; }

// Device-scope coherent 8B load/store: bypass stale per-XCD L2, no wbl2/inv.
__device__ __forceinline__ u64 ld_dev(const u64* p) {
  return __hip_atomic_load(p, __ATOMIC_RELAXED, __HIP_MEMORY_SCOPE_AGENT);
}
__device__ __forceinline__ void st_dev(u64* p, u64 v) {
  __hip_atomic_store(p, v, __ATOMIC_RELAXED, __HIP_MEMORY_SCOPE_AGENT);
}
__device__ __forceinline__ int ld_flag(const int* p) {
  return __hip_atomic_load(p, __ATOMIC_RELAXED, __HIP_MEMORY_SCOPE_AGENT);
}

// ---------------- cast fp32 -> bf16 ----------------
__global__ __launch_bounds__(256) void cast_f32_bf16(const float* __restrict__ in,
                                                     u16* __restrict__ out, int n) {
  int i = (blockIdx.x * 256 + threadIdx.x) * 8;
  if (i + 7 < n) {
    float4 v0 = *reinterpret_cast<const float4*>(in + i);
    float4 v1 = *reinterpret_cast<const float4*>(in + i + 4);
    uint4 o;
    o.x = (unsigned)f2bf(v0.x) | ((unsigned)f2bf(v0.y) << 16);
    o.y = (unsigned)f2bf(v0.z) | ((unsigned)f2bf(v0.w) << 16);
    o.z = (unsigned)f2bf(v1.x) | ((unsigned)f2bf(v1.y) << 16);
    o.w = (unsigned)f2bf(v1.z) | ((unsigned)f2bf(v1.w) << 16);
    *reinterpret_cast<uint4*>(out + i) = o;
  } else {
    for (; i < n; ++i) out[i] = f2bf(in[i]);
  }
}

// ---------------- LSTM input GEMM: out[t][b][k][g] = x @ w_ih^T + b_ih + b_hh ----------------
__global__ __launch_bounds__(256) void gemm_xg(
    const u16* __restrict__ A, const u16* __restrict__ W,
    const float* __restrict__ bias1, const float* __restrict__ bias2,
    u16* __restrict__ out, int N, int K, int strideB, int strideT)
{
  __shared__ u16 As[64][72];
  __shared__ u16 Bs[64][72];
  int tid  = threadIdx.x;
  int lane = tid & 63;
  int wave = tid >> 6;
  int m0 = blockIdx.x * 64;
  int n0 = blockIdx.y * 64;

  f32x4 zero = {0.f, 0.f, 0.f, 0.f};
  f32x4 acc[4] = {zero, zero, zero, zero};

  int srow = tid >> 2;
  int scol = (tid & 3) * 16;

  int m_s = m0 + srow;
  long arow = (long)(m_s & (BATCH - 1)) * strideB + (long)(m_s >> 5) * strideT;
  const u16* aptr = A + arow * K + scol;
  const u16* wptr = W + (long)(n0 + srow) * K + scol;

  for (int kk = 0; kk < K; kk += 64) {
    __syncthreads();
    uint4 a0 = *reinterpret_cast<const uint4*>(aptr + kk);
    uint4 a1 = *reinterpret_cast<const uint4*>(aptr + kk + 8);
    uint4 b0 = *reinterpret_cast<const uint4*>(wptr + kk);
    uint4 b1 = *reinterpret_cast<const uint4*>(wptr + kk + 8);
    *reinterpret_cast<uint4*>(&As[srow][scol])     = a0;
    *reinterpret_cast<uint4*>(&As[srow][scol + 8]) = a1;
    *reinterpret_cast<uint4*>(&Bs[srow][scol])     = b0;
    *reinterpret_cast<uint4*>(&Bs[srow][scol + 8]) = b1;
    __syncthreads();
    int am = wave * 16 + (lane & 15);
    int kq = (lane >> 4) * 8;
#pragma unroll
    for (int ks = 0; ks < 2; ++ks) {
      bf16x8 af = *reinterpret_cast<const bf16x8*>(&As[am][kq + ks * 32]);
#pragma unroll
      for (int nb = 0; nb < 4; ++nb) {
        bf16x8 bf = *reinterpret_cast<const bf16x8*>(&Bs[nb * 16 + (lane & 15)][kq + ks * 32]);
        acc[nb] = __builtin_amdgcn_mfma_f32_16x16x32_bf16(af, bf, acc[nb], 0, 0, 0);
      }
    }
  }
  int quad = lane >> 4;
#pragma unroll
  for (int nb = 0; nb < 4; ++nb) {
    int n = n0 + nb * 16 + (lane & 15);
    float bv = bias1[n] + (bias2 ? bias2[n] : 0.0f);
    int g = n >> 9, k = n & 511;
#pragma unroll
    for (int r = 0; r < 4; ++r) {
      int m = m0 + wave * 16 + quad * 4 + r;
      int t = m >> 5, b = m & (BATCH - 1);
      out[(((long)t * BATCH + b) * HID + k) * 4 + g] = f2bf(acc[nb][r] + bv);
    }
  }
}

// 16x16x32 K=512 fragment GEMM: A rows from coherent global, B from LDS region.
__device__ __forceinline__ f32x4 frag_gemm(const u16* aptr, int kq,
                                           const u16 (*w)[520], int wrow) {
  const u64* xp = reinterpret_cast<const u64*>(aptr);
  f32x4 a0 = {0.f,0.f,0.f,0.f}, a1 = {0.f,0.f,0.f,0.f};
#pragma unroll
  for (int ks = 0; ks < 16; ++ks) {
    union { u64 q[2]; bf16x8 v; } c;
    c.q[0] = ld_dev(xp + ks * 8);
    c.q[1] = ld_dev(xp + ks * 8 + 1);
    bf16x8 bfr = *reinterpret_cast<const bf16x8*>(&w[wrow][kq + ks * 32]);
    if (ks & 1) a1 = __builtin_amdgcn_mfma_f32_16x16x32_bf16(c.v, bfr, a1, 0, 0, 0);
    else        a0 = __builtin_amdgcn_mfma_f32_16x16x32_bf16(c.v, bfr, a0, 0, 0, 0);
  }
  return a0 + a1;
}

// ---------------- persistent recurrent role (ROLE: 0=LSTM 1=GRU 2=RNN) ----------------
// hist is a ring of RH steps; up is a ring of RING steps; cons = downstream
// consumer progress flags (back-pressure before overwriting hist slot).
template <int ROLE>
__device__ void recur_role(
    int wg, const u16* __restrict__ xg, const u16* __restrict__ up,
    const u16* __restrict__ wih, const u16* __restrict__ whh,
    const float* __restrict__ bih, const float* __restrict__ bhh,
    u16* __restrict__ hist, const int* fl_up, int n_up, int* fl_own,
    const int* cons, int n_cons,
    u16 (*w_lds)[520], float (*gx)[33], float (*gh)[33], u16 (*hs)[8])
{
  constexpr int NG = (ROLE == 0) ? 4 : (ROLE == 1) ? 3 : 1;
  constexpr int NPAD = (ROLE == 2) ? 16 : 32;
  constexpr int XROWS = (ROLE > 0) ? NG * 8 : 0;   // x-weight rows staged
  constexpr int TOT = XROWS + NG * 8;
  constexpr int RH = (ROLE == 2) ? 2 : RING;
  int tid = threadIdx.x, lane = tid & 63, wave = tid >> 6;
  int hbase = wg * 8;

  // stage weights compactly: rows [0,XROWS) = w_ih slice, [XROWS,TOT) = w_hh slice
  for (int idx = tid; idx < TOT * 64; idx += 256) {
    int row = idx >> 6, chunk = idx & 63;
    int n = (row < XROWS) ? row : (row - XROWS);
    const u16* src = (row < XROWS) ? wih : whh;
    int g = n >> 3, dd = n & 7;
    uint4 v = *reinterpret_cast<const uint4*>(src + ((long)(g * 512 + hbase + dd)) * 512 + chunk * 8);
    *reinterpret_cast<uint4*>(&w_lds[row][chunk * 8]) = v;
  }
  __syncthreads();

  int mt = wave & 1, nt = wave >> 1;
  bool mact = (nt * 16) < NPAD;
  int colw = nt * 16 + (lane & 15);
  int wr = (colw < NG * 8) ? colw : (NG * 8 - 1);   // clamped B row (cols>=NG*8 unused)
  int arow = mt * 16 + (lane & 15);
  int kq = (lane >> 4) * 8;
  float bxw = 0.f, bhw = 0.f;
  if (colw < NG * 8) {
    int g = colw >> 3, dd = colw & 7;
    if constexpr (ROLE == 1) { bxw = bih[g * 512 + hbase + dd]; bhw = bhh[g * 512 + hbase + dd]; }
    if constexpr (ROLE == 2) { bxw = bih[hbase + dd] + bhh[hbase + dd]; }
    (void)g;
  }
  int b_c = tid >> 3, d_c = tid & 7;   // cell thread owns h[b_c][hbase+d_c]
  float c_st = 0.f, h_st = 0.f;

  for (int t = 0; t < T_SEQ; ++t) {
    u64 xq = 0;
    if constexpr (ROLE == 0)
      xq = *reinterpret_cast<const u64*>(xg + (((long)t * BATCH + b_c) * HID + hbase + d_c) * 4);

    f32x4 aX = {0.f,0.f,0.f,0.f}, aH = {0.f,0.f,0.f,0.f};
    if (mact) {
      if constexpr (ROLE > 0) {
        int tgt = t + 1;
        while (true) {
          int f = tgt;
          if (lane < n_up) f = ld_flag(&fl_up[lane]);
          if (__all(f >= tgt)) break;
          __builtin_amdgcn_s_sleep(1);
        }
        __asm__ volatile("" ::: "memory");
        aX = frag_gemm(up + ((long)(t & (RING - 1)) * BATCH + arow) * HID + kq, kq, w_lds, wr);
      }
      if (t > 0) {
        while (true) {
          int f = ld_flag(&fl_own[lane]);
          if (__all(f >= t)) break;
          __builtin_amdgcn_s_sleep(1);
        }
        __asm__ volatile("" ::: "memory");
        aH = frag_gemm(hist + ((long)((t - 1) & (RH - 1)) * BATCH + arow) * HID + kq,
                       kq, w_lds + XROWS, wr);
      }
      int quad = lane >> 4;
#pragma unroll
      for (int r = 0; r < 4; ++r) {
        int row = mt * 16 + quad * 4 + r;
        gx[row][colw] = aX[r] + bxw;
        gh[row][colw] = aH[r] + bhw;
      }
    }
    __syncthreads();

    float hnew;
    if constexpr (ROLE == 0) {
      float xv0 = bf2f((u16)(xq));
      float xv1 = bf2f((u16)(xq >> 16));
      float xv2 = bf2f((u16)(xq >> 32));
      float xv3 = bf2f((u16)(xq >> 48));
      float h0 = gh[b_c][0 * 8 + d_c];
      float h1 = gh[b_c][1 * 8 + d_c];
      float h2 = gh[b_c][2 * 8 + d_c];
      float h3 = gh[b_c][3 * 8 + d_c];
      float ig = sigf(xv0 + h0), fg = sigf(xv1 + h1);
      float gg = tanh_fast(xv2 + h2), og = sigf(xv3 + h3);
      c_st = fg * c_st + ig * gg;
      hnew = og * tanh_fast(c_st);
    } else if constexpr (ROLE == 1) {
      float xr_ = gx[b_c][0 * 8 + d_c], xz = gx[b_c][1 * 8 + d_c], xn = gx[b_c][2 * 8 + d_c];
      float hr  = gh[b_c][0 * 8 + d_c], hz = gh[b_c][1 * 8 + d_c], hn = gh[b_c][2 * 8 + d_c];
      float r = sigf(xr_ + hr), z = sigf(xz + hz);
      float n = tanh_fast(xn + r * hn);
      hnew = (1.f - z) * n + z * h_st;
      h_st = hnew;
    } else {
      hnew = tanh_fast(gx[b_c][d_c] + gh[b_c][d_c]);
    }
    hs[b_c][d_c] = f2bf(hnew);
    __syncthreads();

    if (wave == 0) {
      // back-pressure: downstream must have consumed step t-RH before we
      // overwrite ring slot t%RH (its old content is step t-RH).
      if (cons != nullptr && t >= RH) {
        int tgt = t - RH + 1;
        while (true) {
          int f = tgt;
          if (lane < n_cons) f = ld_flag(&cons[lane]);
          if (__all(f >= tgt)) break;
          __builtin_amdgcn_s_sleep(1);
        }
      }
      int pb = lane >> 1, half = lane & 1;
      u64 val = *reinterpret_cast<const u64*>(&hs[pb][half * 4]);
      st_dev(reinterpret_cast<u64*>(hist + ((long)(t & (RH - 1)) * BATCH + pb) * HID + hbase + half * 4), val);
      __asm__ volatile("s_waitcnt vmcnt(0)" ::: "memory");
      if (tid == 0)
        __hip_atomic_store(&fl_own[wg], t + 1, __ATOMIC_RELAXED, __HIP_MEMORY_SCOPE_AGENT);
    }
  }
}

// ---------------- pipelined LayerNorm role (4 WGs x 8 rows) ----------------
// in/out are RING-step rings; cons = downstream recur flags (64) for back-pressure.
__device__ void ln_role(int wg, const u16* __restrict__ in, u16* __restrict__ out,
                        const float* __restrict__ gv, const float* __restrict__ bv,
                        const int* fl_in, int* fl_out, const int* cons)
{
  int tid = threadIdx.x, lane = tid & 63, wave = tid >> 6;
  int row = wg * 8 + wave * 2 + (lane >> 5);
  int l32 = lane & 31, k0 = l32 * 16;
  float gr[16], br[16];
#pragma unroll
  for (int j = 0; j < 16; ++j) { gr[j] = gv[k0 + j]; br[j] = bv[k0 + j]; }

  for (int t = 0; t < T_SEQ; ++t) {
    int tgt = t + 1;
    while (true) {
      int f = ld_flag(&fl_in[lane]);
      if (__all(f >= tgt)) break;
      __builtin_amdgcn_s_sleep(1);
    }
    if (t >= RING) {
      int tg2 = t - RING + 1;
      while (true) {
        int f = ld_flag(&cons[lane]);
        if (__all(f >= tg2)) break;
        __builtin_amdgcn_s_sleep(1);
      }
    }
    __asm__ volatile("" ::: "memory");
    const u64* p = reinterpret_cast<const u64*>(in + ((long)(t & (RING - 1)) * BATCH + row) * HID + k0);
    u64 q[4];
#pragma unroll
    for (int i = 0; i < 4; ++i) q[i] = ld_dev(p + i);
    float x[16];
#pragma unroll
    for (int i = 0; i < 16; ++i) x[i] = bf2f((u16)(q[i >> 2] >> (16 * (i & 3))));
    float s = 0.f, s2 = 0.f;
#pragma unroll
    for (int i = 0; i < 16; ++i) { s += x[i]; s2 += x[i] * x[i]; }
#pragma unroll
    for (int off = 1; off < 32; off <<= 1) { s += __shfl_xor(s, off); s2 += __shfl_xor(s2, off); }
    float mu = s * (1.f / 512.f);
    float var = s2 * (1.f / 512.f) - mu * mu;
    float rs = rsqrtf(var + 1e-5f);
    u16 o[16];
#pragma unroll
    for (int i = 0; i < 16; ++i) o[i] = f2bf((x[i] - mu) * rs * gr[i] + br[i]);
    u64* po = reinterpret_cast<u64*>(out + ((long)(t & (RING - 1)) * BATCH + row) * HID + k0);
    const u64* oq = reinterpret_cast<const u64*>(o);
#pragma unroll
    for (int i = 0; i < 4; ++i) st_dev(po + i, oq[i]);
    __asm__ volatile("s_waitcnt vmcnt(0)" ::: "memory");
    __syncthreads();
    if (tid == 0)
      __hip_atomic_store(&fl_out[wg], t + 1, __ATOMIC_RELAXED, __HIP_MEMORY_SCOPE_AGENT);
  }
}

// ---------------- fused pipeline kernel: 200 WGs ----------------
// flags: [0..63] lstm, [64..67] ln1, [128..191] gru, [192..195] ln2, [256..319] rnn
__global__ __launch_bounds__(256) void fused_kernel(
    const u16* __restrict__ xg, const u16* __restrict__ lstm_whh,
    const u16* __restrict__ gru_wih, const u16* __restrict__ gru_whh,
    const float* __restrict__ gru_bih, const float* __restrict__ gru_bhh,
    const u16* __restrict__ rnn_wih, const u16* __restrict__ rnn_whh,
    const float* __restrict__ rnn_bih, const float* __restrict__ rnn_bhh,
    const float* __restrict__ ln1_g, const float* __restrict__ ln1_b,
    const float* __restrict__ ln2_g, const float* __restrict__ ln2_b,
    u16* h1, u16* ln1o, u16* h2, u16* ln2o, u16* h3, int* fl)
{
  __shared__ u16 w_lds[48][520];     // 49.9 KB  (total static LDS 58.9 KB < 64 KB)
  __shared__ float gx[32][33];       // 4.2 KB
  __shared__ float gh[32][33];       // 4.2 KB
  __shared__ u16 hs[32][8];          // 0.5 KB
  int bid = blockIdx.x;
  if (bid < 64)
    recur_role<0>(bid, xg, nullptr, nullptr, lstm_whh, nullptr, nullptr,
                  h1, nullptr, 0, fl + 0, fl + 64, 4, w_lds, gx, gh, hs);
  else if (bid < 68)
    ln_role(bid - 64, h1, ln1o, ln1_g, ln1_b, fl + 0, fl + 64, fl + 128);
  else if (bid < 132)
    recur_role<1>(bid - 68, nullptr, ln1o, gru_wih, gru_whh, gru_bih, gru_bhh,
                  h2, fl + 64, 4, fl + 128, fl + 192, 4, w_lds, gx, gh, hs);
  else if (bid < 136)
    ln_role(bid - 132, h2, ln2o, ln2_g, ln2_b, fl + 128, fl + 192, fl + 256);
  else
    recur_role<2>(bid - 136, nullptr, ln2o, rnn_wih, rnn_whh, rnn_bih, rnn_bhh,
                  h3, fl + 192, 4, fl + 256, nullptr, 0, w_lds, gx, gh, hs);
}

// ---------------- final FC ----------------
__global__ __launch_bounds__(256) void fc_kernel(
    const u16* __restrict__ hlast, const u16* __restrict__ w,
    const float* __restrict__ bias, float* __restrict__ out)
{
  int tg = blockIdx.x * 256 + threadIdx.x;
  if (tg >= BATCH * 1000) return;
  int b = tg / 1000, o = tg % 1000;
  const u16* hp = hlast + (long)b * HID;
  const u16* wp = w + (long)o * HID;
  float acc = 0.f;
  for (int k = 0; k < HID; k += 8) {
    uint4 hu = *reinterpret_cast<const uint4*>(hp + k);
    uint4 wu = *reinterpret_cast<const uint4*>(wp + k);
    u16* hsv = reinterpret_cast<u16*>(&hu);
    u16* wsv = reinterpret_cast<u16*>(&wu);
#pragma unroll
    for (int i = 0; i < 8; ++i) acc += bf2f(hsv[i]) * bf2f(wsv[i]);
  }
  out[tg] = acc + bias[o];
}

__global__ void sentinel_kernel(float* out) { out[0] = 12345.0f; }

// ---------------- launch ----------------
extern "C" void kernel_launch(void* const* d_in, const int* in_sizes, int n_in,
                              void* d_out, int out_size, void* d_ws, size_t ws_size,
                              hipStream_t stream)
{
  (void)in_sizes; (void)n_in; (void)out_size;
  const float* x        = (const float*)d_in[0];
  const float* lstm_wih = (const float*)d_in[1];
  const float* lstm_whh = (const float*)d_in[2];
  const float* lstm_bih = (const float*)d_in[3];
  const float* lstm_bhh = (const float*)d_in[4];
  const float* ln1_g    = (const float*)d_in[5];
  const float* ln1_b    = (const float*)d_in[6];
  const float* gru_wih  = (const float*)d_in[7];
  const float* gru_whh  = (const float*)d_in[8];
  const float* gru_bih  = (const float*)d_in[9];
  const float* gru_bhh  = (const float*)d_in[10];
  const float* ln2_g    = (const float*)d_in[11];
  const float* ln2_b    = (const float*)d_in[12];
  const float* rnn_wih  = (const float*)d_in[13];
  const float* rnn_whh  = (const float*)d_in[14];
  const float* rnn_bih  = (const float*)d_in[15];
  const float* rnn_bhh  = (const float*)d_in[16];
  const float* fc_w     = (const float*)d_in[17];
  const float* fc_b     = (const float*)d_in[18];
  float* out = (float*)d_out;

  char* ws = (char*)d_ws;
  size_t off = 0;
  auto alloc = [&](size_t bytes) -> void* {
    void* p = ws + off; off += (bytes + 255) & ~(size_t)255; return p;
  };
  int* flags     = (int*)alloc(320 * sizeof(int));
  u16* xbf       = (u16*)alloc((size_t)BATCH * T_SEQ * 256 * 2);
  u16* lstm_wih_b= (u16*)alloc((size_t)2048 * 256 * 2);
  u16* lstm_whh_b= (u16*)alloc((size_t)2048 * 512 * 2);
  u16* gru_wih_b = (u16*)alloc((size_t)1536 * 512 * 2);
  u16* gru_whh_b = (u16*)alloc((size_t)1536 * 512 * 2);
  u16* rnn_wih_b = (u16*)alloc((size_t)512 * 512 * 2);
  u16* rnn_whh_b = (u16*)alloc((size_t)512 * 512 * 2);
  u16* fc_w_b    = (u16*)alloc((size_t)1000 * 512 * 2);
  u16* xg2       = (u16*)alloc((size_t)T_SEQ * BATCH * HID * 4 * 2);  // 128 MB
  u16* h1        = (u16*)alloc((size_t)RING * BATCH * HID * 2);       // 1 MB rings
  u16* ln1o      = (u16*)alloc((size_t)RING * BATCH * HID * 2);
  u16* h2        = (u16*)alloc((size_t)RING * BATCH * HID * 2);
  u16* ln2o      = (u16*)alloc((size_t)RING * BATCH * HID * 2);
  u16* h3        = (u16*)alloc((size_t)2 * BATCH * HID * 2);          // ping-pong

  if (off > ws_size) {
    sentinel_kernel<<<1, 1, 0, stream>>>(out);
    return;
  }

  hipMemsetAsync(flags, 0, 320 * sizeof(int), stream);

  auto cast = [&](const float* src, u16* dst, int n) {
    cast_f32_bf16<<<(n + 2047) / 2048, 256, 0, stream>>>(src, dst, n);
  };
  cast(x,        xbf,        BATCH * T_SEQ * 256);
  cast(lstm_wih, lstm_wih_b, 2048 * 256);
  cast(lstm_whh, lstm_whh_b, 2048 * 512);
  cast(gru_wih,  gru_wih_b,  1536 * 512);
  cast(gru_whh,  gru_whh_b,  1536 * 512);
  cast(rnn_wih,  rnn_wih_b,  512 * 512);
  cast(rnn_whh,  rnn_whh_b,  512 * 512);
  cast(fc_w,     fc_w_b,     1000 * 512);

  const int M64 = (BATCH * T_SEQ) / 64;  // 512
  gemm_xg<<<dim3(M64, 2048 / 64), 256, 0, stream>>>(
      xbf, lstm_wih_b, lstm_bih, lstm_bhh, xg2, 2048, 256, 1024, 1);

  fused_kernel<<<200, 256, 0, stream>>>(
      xg2, lstm_whh_b,
      gru_wih_b, gru_whh_b, gru_bih, gru_bhh,
      rnn_wih_b, rnn_whh_b, rnn_bih, rnn_bhh,
      ln1_g, ln1_b, ln2_g, ln2_b,
      h1, ln1o, h2, ln2o, h3, flags);

  // h3 last written slot = (T_SEQ-1)&1 = 1
  fc_kernel<<<(BATCH * 1000 + 255) / 256, 256, 0, stream>>>(
      h3 + (size_t)BATCH * HID, fc_w_b, fc_b, out);
}